// Round 1
// baseline (282.297 us; speedup 1.0000x reference)
//
#include <hip/hip_runtime.h>
#include <math.h>

// Problem: B=4096 rows, C=8192 cols, f32. Scalar output = mean over all
// (row, positive) pairs of log1p(exp(lse_neg(row) - x_p)).
// weights input is mathematically unused (CE weight cancels for 1 sample).

#define ROWS 4096
#define COLS 8192
#define TPB  256
#define VEC_ITERS (COLS / (TPB * 4))   // 8 float4 loads per thread
#define EPT (VEC_ITERS * 4)            // 32 elements per thread

__device__ __forceinline__ float waveMax(float v) {
#pragma unroll
    for (int off = 32; off > 0; off >>= 1)
        v = fmaxf(v, __shfl_xor(v, off, 64));
    return v;
}

__device__ __forceinline__ float waveSum(float v) {
#pragma unroll
    for (int off = 32; off > 0; off >>= 1)
        v += __shfl_xor(v, off, 64);
    return v;
}

__global__ __launch_bounds__(TPB) void row_loss_kernel(
        const float* __restrict__ logits,
        const float* __restrict__ target,
        float* __restrict__ ws_loss,
        float* __restrict__ ws_cnt) {
    const int row = blockIdx.x;
    const int tid = threadIdx.x;
    const int wave = tid >> 6;

    const float4* __restrict__ orow =
        (const float4*)(logits + (size_t)row * COLS);
    const float4* __restrict__ trow =
        (const float4*)(target + (size_t)row * COLS);

    // Single pass over HBM: keep 32 values in registers + 32-bit positive mask.
    float vals[EPT];
    unsigned mask = 0;
#pragma unroll
    for (int i = 0; i < VEC_ITERS; i++) {
        float4 o = orow[tid + i * TPB];
        float4 t = trow[tid + i * TPB];
        vals[i * 4 + 0] = o.x;
        vals[i * 4 + 1] = o.y;
        vals[i * 4 + 2] = o.z;
        vals[i * 4 + 3] = o.w;
        if (t.x != 0.f) mask |= 1u << (i * 4 + 0);
        if (t.y != 0.f) mask |= 1u << (i * 4 + 1);
        if (t.z != 0.f) mask |= 1u << (i * 4 + 2);
        if (t.w != 0.f) mask |= 1u << (i * 4 + 3);
    }

    __shared__ float sred[8];

    // --- Pass A: block max over negatives ---
    float m = -INFINITY;
#pragma unroll
    for (int j = 0; j < EPT; j++)
        if (!((mask >> j) & 1u)) m = fmaxf(m, vals[j]);
    float wm = waveMax(m);
    if ((tid & 63) == 0) sred[wave] = wm;
    __syncthreads();
    const float bm = fmaxf(fmaxf(sred[0], sred[1]), fmaxf(sred[2], sred[3]));
    __syncthreads();

    // --- Pass B: block sum of exp(x - bm) over negatives ---
    float s = 0.f;
#pragma unroll
    for (int j = 0; j < EPT; j++)
        if (!((mask >> j) & 1u)) s += expf(vals[j] - bm);
    float ws = waveSum(s);
    if ((tid & 63) == 0) sred[wave] = ws;
    __syncthreads();
    const float S = sred[0] + sred[1] + sred[2] + sred[3];
    const float lse = bm + logf(S);
    __syncthreads();

    // --- Pass C: positives: log1p(exp(lse - x_p)) ---
    float loss = 0.f, cnt = 0.f;
#pragma unroll
    for (int j = 0; j < EPT; j++)
        if ((mask >> j) & 1u) {
            loss += log1pf(expf(lse - vals[j]));
            cnt += 1.f;
        }
    loss = waveSum(loss);
    cnt  = waveSum(cnt);
    if ((tid & 63) == 0) { sred[wave] = loss; sred[4 + wave] = cnt; }
    __syncthreads();
    if (tid == 0) {
        ws_loss[row] = sred[0] + sred[1] + sred[2] + sred[3];
        ws_cnt[row]  = sred[4] + sred[5] + sred[6] + sred[7];
    }
}

__global__ __launch_bounds__(TPB) void finalize_kernel(
        const float* __restrict__ ws_loss,
        const float* __restrict__ ws_cnt,
        float* __restrict__ out) {
    const int tid = threadIdx.x;
    float l = 0.f, c = 0.f;
    for (int i = tid; i < ROWS; i += TPB) {
        l += ws_loss[i];
        c += ws_cnt[i];
    }
    l = waveSum(l);
    c = waveSum(c);
    __shared__ float sl[4], sc[4];
    if ((tid & 63) == 0) { sl[tid >> 6] = l; sc[tid >> 6] = c; }
    __syncthreads();
    if (tid == 0) {
        float L = sl[0] + sl[1] + sl[2] + sl[3];
        float N = sc[0] + sc[1] + sc[2] + sc[3];
        out[0] = L / N;
    }
}

extern "C" void kernel_launch(void* const* d_in, const int* in_sizes, int n_in,
                              void* d_out, int out_size, void* d_ws, size_t ws_size,
                              hipStream_t stream) {
    const float* logits = (const float*)d_in[0];   // [B, C]
    const float* target = (const float*)d_in[1];   // [B, C]
    // d_in[2] (weights) is unused: per-sample CE weight cancels out.
    float* ws_loss = (float*)d_ws;                 // [ROWS]
    float* ws_cnt  = ws_loss + ROWS;               // [ROWS]

    row_loss_kernel<<<ROWS, TPB, 0, stream>>>(logits, target, ws_loss, ws_cnt);
    finalize_kernel<<<1, TPB, 0, stream>>>(ws_loss, ws_cnt, (float*)d_out);
}